// Round 5
// baseline (236.996 us; speedup 1.0000x reference)
//
#include <hip/hip_runtime.h>

// CtaPostAttnMixer: y = (I + 0.1*Lap)^4 x along l, boundaries l=0, L-1 fixed.
// One 9-tap convolution (interior) + analytic boundary rows.
// x: (B=4, L=8192, D=1024) f32, D contiguous.
//
// R3/R5/R6: register-held windows get serialized by the allocator ->
//   latency wall ~2.5 TB/s. Registers are a dead end for the window.
// R7: LDS staging via global_load_lds (40-row x 64-quad tile, amp 1.25):
//   mixer ~72us (inferred: total-155.6). Demand 288 MB -> 16 GB/s/CU =
//   62% of the 26 GB/s/CU copy ceiling. Per-block critical path ~0.8us
//   << pacing -> memory underfed. Diagnosis: BURSTY issue. Each block
//   issues 40 KB then its load queue is silent through drain+compute+
//   store; 4 blocks/CU doesn't smooth it.
// R8 (this round): persistent 2-phase double-buffered march (T3 minimum
//   recipe). 512 blocks = exactly 2/CU co-resident; each marches 8
//   consecutive 32-row tiles in one column strip. Per iter: issue
//   stage(t+1) -> buf^1, compute tile t from buf^0, barrier. Next-tile
//   loads (40 KB/block) stay in flight under compute -> continuous load
//   issue. Consecutive tiles also make the 8-row halo refetch L1-hot.
//   Predict mixer ~50us, total ~207us. Null (=228) would indict a mixed
//   R/W path ceiling instead -> next step amp 1.0, not scheduling.

namespace {

constexpr int Lr   = 8192;           // sequence length
constexpr int Dq   = 1024 / 4;       // float4 columns = 256
constexpr int Bn   = 4;              // batch
constexpr int R    = 32;             // output rows per tile
constexpr int WR   = R + 8;          // staged rows (4-halo each side) = 40
constexpr int CW   = 64;             // float4 columns per block (1 KB rows)
constexpr int RT   = Lr / R;         // 256 row tiles per strip
constexpr int CT   = Dq / CW;        // 4 col tiles
constexpr int MT   = 8;              // tiles marched per block
constexpr int NXCD = 8;
constexpr int NWG  = RT * CT * Bn / MT;  // 512 blocks = 2/CU, % 8 == 0

// standard 9-tap weights of (I + a*Lap)^4, a = 0.1 (exact: p=[.1,.8,.1]^*4)
constexpr float WK0 = 0.4870f;
constexpr float WK1 = 0.2144f;
constexpr float WK2 = 0.0388f;
constexpr float WK3 = 0.0032f;
constexpr float WK4 = 0.0001f;

__device__ __forceinline__ float4 f4_add(float4 a, float4 b) {
    return make_float4(a.x + b.x, a.y + b.y, a.z + b.z, a.w + b.w);
}
__device__ __forceinline__ float4 f4_mul(float s, float4 a) {
    return make_float4(s * a.x, s * a.y, s * a.z, s * a.w);
}
__device__ __forceinline__ float4 f4_fma(float s, float4 a, float4 c) {
    return make_float4(fmaf(s, a.x, c.x), fmaf(s, a.y, c.y),
                       fmaf(s, a.z, c.z), fmaf(s, a.w, c.w));
}

__global__ __launch_bounds__(256, 2)   // 2 blocks/CU (LDS-limited), VGPR free
void mixer4_kernel(const float4* __restrict__ x, float4* __restrict__ y) {
    __shared__ float4 buf[2][WR][CW];  // 2 x 40 KB double buffer

    // XCD-aware bijective swizzle (NWG=512, %8==0): XCD k owns 64
    // consecutive work ids -> adjacent march ranges (which share halo
    // boundary rows) and whole strips stay in one XCD's L2.
    const int lin   = blockIdx.x;                      // 0..511
    const int g     = (lin & (NXCD - 1)) * (NWG / NXCD) + (lin >> 3);
    const int strip = g >> 5;            // g / 32   (32 blocks per strip)
    const int mrch  = g & 31;            // march index within strip
    const int ct    = strip & (CT - 1);
    const int b     = strip >> 2;
    const int rt0   = mrch * MT;         // first row-tile of this march

    const size_t origin = (size_t)b * Lr * Dq + (size_t)ct * CW;
    const float4* __restrict__ xt = x + origin;
    float4* __restrict__       yt = y + origin;

    const int lane = threadIdx.x & 63;   // column within strip
    const int wid  = threadIdx.x >> 6;   // wave 0..3

    // ---- stage one 40-row tile into buf[sel]: fire-and-forget DMA -------
    auto stage = [&](int rt, int sel) {
        const int r0 = rt * R;
#pragma unroll
        for (int ii = 0; ii < WR / 4; ++ii) {
            const int i  = wid + ii * 4;               // rows 0..39, once each
            int grow = r0 - 4 + i;
            grow = grow < 0 ? 0 : grow;
            grow = grow > Lr - 1 ? Lr - 1 : grow;
            const float4* src = xt + (size_t)grow * Dq + lane;
            __builtin_amdgcn_global_load_lds(
                (const __attribute__((address_space(1))) void*)src,
                (__attribute__((address_space(3))) void*)&buf[sel][i][0],
                16, 0, 0);
        }
    };

    // ---- compute one tile from buf[sel]: wave w -> local rows w*8..w*8+7
    auto compute = [&](int rt, int sel) {
        const int r0    = rt * R;
        const int kbase = wid * 8;
        float4 win[16];
#pragma unroll
        for (int i = 0; i < 16; ++i) win[i] = buf[sel][kbase + i][lane];

        auto interior = [&](int j) {     // j compile-time after unroll
            float4 acc = f4_mul(WK0, win[j + 4]);
            acc = f4_fma(WK1, f4_add(win[j + 3], win[j + 5]), acc);
            acc = f4_fma(WK2, f4_add(win[j + 2], win[j + 6]), acc);
            acc = f4_fma(WK3, f4_add(win[j + 1], win[j + 7]), acc);
            acc = f4_fma(WK4, f4_add(win[j + 0], win[j + 8]), acc);
            yt[(size_t)(r0 + kbase + j) * Dq + lane] = acc;
        };

        const bool low  = (rt == 0)      && (wid == 0);  // global rows 0..7
        const bool high = (rt == RT - 1) && (wid == 3);  // rows L-8..L-1

        if (low) {
            // win[4+m] = x[m] (rows -4..-1 staged as clamped dups of x[0])
            yt[0 * (size_t)Dq + lane] = win[4];          // l=0: copy
            {   // l=1
                float4 o = f4_mul(0.2986f, win[4]);
                o = f4_fma(0.4482f, win[5], o);
                o = f4_fma(0.2112f, win[6], o);
                o = f4_fma(0.0387f, win[7], o);
                o = f4_fma(0.0032f, win[8], o);
                o = f4_fma(0.0001f, win[9], o);
                yt[1 * (size_t)Dq + lane] = o;
            }
            {   // l=2
                float4 o = f4_mul(0.0454f, win[4]);
                o = f4_fma(0.2112f, win[5], o);
                o = f4_fma(0.4869f, win[6], o);
                o = f4_fma(0.2144f, win[7], o);
                o = f4_fma(0.0388f, win[8], o);
                o = f4_fma(0.0032f, win[9], o);
                o = f4_fma(0.0001f, win[10], o);
                yt[2 * (size_t)Dq + lane] = o;
            }
            {   // l=3
                float4 o = f4_mul(0.0034f, win[4]);
                o = f4_fma(0.0387f, win[5], o);
                o = f4_fma(0.2144f, win[6], o);
                o = f4_fma(0.4870f, win[7], o);
                o = f4_fma(0.2144f, win[8], o);
                o = f4_fma(0.0388f, win[9], o);
                o = f4_fma(0.0032f, win[10], o);
                o = f4_fma(0.0001f, win[11], o);
                yt[3 * (size_t)Dq + lane] = o;
            }
#pragma unroll
            for (int j = 4; j < 8; ++j) interior(j);     // rows 4..7 standard
        } else if (high) {
#pragma unroll
            for (int j = 0; j < 4; ++j) interior(j);     // rows L-8..L-5
            // win[4+m] = x[L-8+m]
            yt[(size_t)(Lr - 1) * Dq + lane] = win[11];  // l=L-1: copy
            {   // l=L-2 (mirrored row1)
                float4 o = f4_mul(0.2986f, win[11]);
                o = f4_fma(0.4482f, win[10], o);
                o = f4_fma(0.2112f, win[9], o);
                o = f4_fma(0.0387f, win[8], o);
                o = f4_fma(0.0032f, win[7], o);
                o = f4_fma(0.0001f, win[6], o);
                yt[(size_t)(Lr - 2) * Dq + lane] = o;
            }
            {   // l=L-3 (mirrored row2)
                float4 o = f4_mul(0.0454f, win[11]);
                o = f4_fma(0.2112f, win[10], o);
                o = f4_fma(0.4869f, win[9], o);
                o = f4_fma(0.2144f, win[8], o);
                o = f4_fma(0.0388f, win[7], o);
                o = f4_fma(0.0032f, win[6], o);
                o = f4_fma(0.0001f, win[5], o);
                yt[(size_t)(Lr - 3) * Dq + lane] = o;
            }
            {   // l=L-4 (mirrored row3)
                float4 o = f4_mul(0.0034f, win[11]);
                o = f4_fma(0.0387f, win[10], o);
                o = f4_fma(0.2144f, win[9], o);
                o = f4_fma(0.4870f, win[8], o);
                o = f4_fma(0.2144f, win[7], o);
                o = f4_fma(0.0388f, win[6], o);
                o = f4_fma(0.0032f, win[5], o);
                o = f4_fma(0.0001f, win[4], o);
                yt[(size_t)(Lr - 4) * Dq + lane] = o;
            }
        } else {
#pragma unroll
            for (int j = 0; j < 8; ++j) interior(j);
        }
    };

    // ---- 2-phase pipelined march ----------------------------------------
    stage(rt0, 0);
    __syncthreads();                       // drain prologue loads
    for (int t = 0; t < MT; ++t) {
        const int cur = t & 1;
        if (t + 1 < MT) stage(rt0 + t + 1, cur ^ 1);  // issue BEFORE compute
        compute(rt0 + t, cur);
        __syncthreads();                   // drains vmcnt -> buf^1 ready
    }
}

}  // namespace

extern "C" void kernel_launch(void* const* d_in, const int* in_sizes, int n_in,
                              void* d_out, int out_size, void* d_ws, size_t ws_size,
                              hipStream_t stream) {
    const float4* x = (const float4*)d_in[0];
    float4*       y = (float4*)d_out;

    dim3 grid(NWG);        // 512 persistent blocks = 2/CU, fully co-resident
    dim3 block(256);
    hipLaunchKernelGGL(mixer4_kernel, grid, block, 0, stream, x, y);
}

// Round 6
// 232.550 us; speedup vs baseline: 1.0191x; 1.0191x over previous
//
#include <hip/hip_runtime.h>

// CtaPostAttnMixer: y = (I + 0.1*Lap)^4 x along l, boundaries l=0, L-1 fixed.
// One 9-tap convolution (interior) + analytic boundary rows.
// x: (B=4, L=8192, D=1024) f32, D contiguous.
//
// R3/R5/R6: register-held windows get serialized by the allocator ->
//   latency wall. Registers are a dead end for the window; LDS works.
// R7: LDS 40KB tile, amp 1.25, 4 blocks/CU (50% occ): mixer ~72us,
//   demand rate 4.0 TB/s.
// R8: persistent 2/CU + 2-deep "pipeline": 83us. The per-tile
//   __syncthreads drains vmcnt(0) including the prefetch (structural,
//   and a TRUE dep at depth 2) -> no overlap, and occupancy fell to 18%.
// Occupancy->demand-rate series (same structure family):
//   77% occ -> 6.7 TB/s | 50% -> 4.0 | 18% -> 3.5.  The vector-memory
//   demand path needs ~24+ waves/CU of TLP to saturate ~6.7 TB/s.
// R9 (this round): keep amp 1.25 LDS staging but at HIGH occupancy.
//   CW 64->32: 20 KB tile -> launch_bounds(256,7) = 7 blocks/CU =
//   28 waves/CU (87%). One tile per block, single barrier, 8192 blocks.
//   DMA still 1 KB/issue (row PAIR per issue: per-lane source row
//   i+(lane>>5), wave-uniform LDS dest). Predict: 288 MB demand at
//   ~6.5 TB/s -> mixer ~45-50us, total ~200-206us. Null (>=65us) kills
//   the occupancy theory -> try buffer_load->ds_write relay staging.

namespace {

constexpr int Lr   = 8192;           // sequence length
constexpr int Dq   = 1024 / 4;       // float4 columns = 256
constexpr int Bn   = 4;              // batch
constexpr int R    = 32;             // output rows per block
constexpr int WR   = R + 8;          // staged rows = 40
constexpr int CW   = 32;             // float4 columns per block (512 B rows)
constexpr int RT   = Lr / R;         // 256 row tiles
constexpr int CT   = Dq / CW;        // 8 col tiles
constexpr int NXCD = 8;
constexpr int NWG  = RT * CT * Bn;   // 8192 blocks, % 8 == 0 -> bijective

// standard 9-tap weights of (I + a*Lap)^4, a = 0.1 (exact: p=[.1,.8,.1]^*4)
constexpr float WK0 = 0.4870f;
constexpr float WK1 = 0.2144f;
constexpr float WK2 = 0.0388f;
constexpr float WK3 = 0.0032f;
constexpr float WK4 = 0.0001f;

__device__ __forceinline__ float4 f4_add(float4 a, float4 b) {
    return make_float4(a.x + b.x, a.y + b.y, a.z + b.z, a.w + b.w);
}
__device__ __forceinline__ float4 f4_mul(float s, float4 a) {
    return make_float4(s * a.x, s * a.y, s * a.z, s * a.w);
}
__device__ __forceinline__ float4 f4_fma(float s, float4 a, float4 c) {
    return make_float4(fmaf(s, a.x, c.x), fmaf(s, a.y, c.y),
                       fmaf(s, a.z, c.z), fmaf(s, a.w, c.w));
}

__global__ __launch_bounds__(256, 7)   // 7 blocks/CU: 28 waves (87%), VGPR<=73
void mixer4_kernel(const float4* __restrict__ x, float4* __restrict__ y) {
    __shared__ float4 tile[WR][CW];    // 20 KB, rows contiguous (512 B)

    // XCD-aware bijective swizzle: XCD k owns contiguous work ids; rt is
    // fastest -> adjacent row-tiles (sharing 8 halo rows) on one XCD/L2.
    const int lin = blockIdx.x;                        // 0..NWG-1
    const int g   = (lin & (NXCD - 1)) * (NWG / NXCD) + (lin >> 3);
    const int rt  = g & (RT - 1);                      // row tile
    const int bc  = g >> 8;
    const int ct  = bc & (CT - 1);
    const int b   = bc >> 3;
    const int r0  = rt * R;

    const size_t origin = (size_t)b * Lr * Dq + (size_t)ct * CW;
    const float4* __restrict__ xt = x + origin;
    float4* __restrict__       yt = y + origin;

    const int lane = threadIdx.x & 63;
    const int wid  = threadIdx.x >> 6;                 // wave 0..3

    // ---- stage 40 rows as 20 row-pair DMAs (1 KB each) -------------------
    // LDS dest wave-uniform (&tile[2p][0]); lanes 0-31 -> row 2p cols 0-31,
    // lanes 32-63 -> row 2p+1 (per-lane global source rows are legal).
#pragma unroll
    for (int ii = 0; ii < 5; ++ii) {
        const int p = wid + ii * 4;                    // 0..19, once each
        int grow = r0 - 4 + 2 * p + (lane >> 5);
        grow = grow < 0 ? 0 : grow;
        grow = grow > Lr - 1 ? Lr - 1 : grow;
        const float4* src = xt + (size_t)grow * Dq + (lane & 31);
        __builtin_amdgcn_global_load_lds(
            (const __attribute__((address_space(1))) void*)src,
            (__attribute__((address_space(3))) void*)&tile[2 * p][0],
            16, 0, 0);
    }
    __syncthreads();   // drains vmcnt -> tile ready

    // ---- compute: thread = (col c, rowgroup gr); 4 output rows each ------
    const int c  = threadIdx.x & 31;
    const int gr = threadIdx.x >> 5;                   // 0..7
    float4 win[12];                                    // LDS rows 4gr..4gr+11
#pragma unroll
    for (int i = 0; i < 12; ++i) win[i] = tile[4 * gr + i][c];
    // win[i] = x[r0 + 4gr - 4 + i (clamped)]

    auto interior = [&](int j) {       // output local row 4gr+j
        float4 acc = f4_mul(WK0, win[j + 4]);
        acc = f4_fma(WK1, f4_add(win[j + 3], win[j + 5]), acc);
        acc = f4_fma(WK2, f4_add(win[j + 2], win[j + 6]), acc);
        acc = f4_fma(WK3, f4_add(win[j + 1], win[j + 7]), acc);
        acc = f4_fma(WK4, f4_add(win[j + 0], win[j + 8]), acc);
        yt[(size_t)(r0 + 4 * gr + j) * Dq + c] = acc;
    };

    const bool low  = (rt == 0)      && (gr == 0);     // global rows 0..3
    const bool high = (rt == RT - 1) && (gr == 7);     // rows L-4..L-1

    if (low) {
        // win[4+m] = x[m] (rows -4..-1 staged as clamped dups of x[0])
        yt[0 * (size_t)Dq + c] = win[4];               // l=0: copy
        {   // l=1
            float4 o = f4_mul(0.2986f, win[4]);
            o = f4_fma(0.4482f, win[5], o);
            o = f4_fma(0.2112f, win[6], o);
            o = f4_fma(0.0387f, win[7], o);
            o = f4_fma(0.0032f, win[8], o);
            o = f4_fma(0.0001f, win[9], o);
            yt[1 * (size_t)Dq + c] = o;
        }
        {   // l=2
            float4 o = f4_mul(0.0454f, win[4]);
            o = f4_fma(0.2112f, win[5], o);
            o = f4_fma(0.4869f, win[6], o);
            o = f4_fma(0.2144f, win[7], o);
            o = f4_fma(0.0388f, win[8], o);
            o = f4_fma(0.0032f, win[9], o);
            o = f4_fma(0.0001f, win[10], o);
            yt[2 * (size_t)Dq + c] = o;
        }
        {   // l=3
            float4 o = f4_mul(0.0034f, win[4]);
            o = f4_fma(0.0387f, win[5], o);
            o = f4_fma(0.2144f, win[6], o);
            o = f4_fma(0.4870f, win[7], o);
            o = f4_fma(0.2144f, win[8], o);
            o = f4_fma(0.0388f, win[9], o);
            o = f4_fma(0.0032f, win[10], o);
            o = f4_fma(0.0001f, win[11], o);
            yt[3 * (size_t)Dq + c] = o;
        }
    } else if (high) {
        // gr==7 at last tile: win[i] = x[L-8+i] for i=0..7 (8..11 clamped dups)
        yt[(size_t)(Lr - 1) * Dq + c] = win[7];        // l=L-1: copy
        {   // l=L-2 (mirrored row1)
            float4 o = f4_mul(0.2986f, win[7]);
            o = f4_fma(0.4482f, win[6], o);
            o = f4_fma(0.2112f, win[5], o);
            o = f4_fma(0.0387f, win[4], o);
            o = f4_fma(0.0032f, win[3], o);
            o = f4_fma(0.0001f, win[2], o);
            yt[(size_t)(Lr - 2) * Dq + c] = o;
        }
        {   // l=L-3 (mirrored row2)
            float4 o = f4_mul(0.0454f, win[7]);
            o = f4_fma(0.2112f, win[6], o);
            o = f4_fma(0.4869f, win[5], o);
            o = f4_fma(0.2144f, win[4], o);
            o = f4_fma(0.0388f, win[3], o);
            o = f4_fma(0.0032f, win[2], o);
            o = f4_fma(0.0001f, win[1], o);
            yt[(size_t)(Lr - 3) * Dq + c] = o;
        }
        {   // l=L-4 (mirrored row3)
            float4 o = f4_mul(0.0034f, win[7]);
            o = f4_fma(0.0387f, win[6], o);
            o = f4_fma(0.2144f, win[5], o);
            o = f4_fma(0.4870f, win[4], o);
            o = f4_fma(0.2144f, win[3], o);
            o = f4_fma(0.0388f, win[2], o);
            o = f4_fma(0.0032f, win[1], o);
            o = f4_fma(0.0001f, win[0], o);
            yt[(size_t)(Lr - 4) * Dq + c] = o;
        }
    } else {
#pragma unroll
        for (int j = 0; j < 4; ++j) interior(j);
    }
}

}  // namespace

extern "C" void kernel_launch(void* const* d_in, const int* in_sizes, int n_in,
                              void* d_out, int out_size, void* d_ws, size_t ws_size,
                              hipStream_t stream) {
    const float4* x = (const float4*)d_in[0];
    float4*       y = (float4*)d_out;

    dim3 grid(NWG);        // 8192 blocks, 1D so the swizzle owns the mapping
    dim3 block(256);
    hipLaunchKernelGGL(mixer4_kernel, grid, block, 0, stream, x, y);
}